// Round 1
// baseline (478.705 us; speedup 1.0000x reference)
//
#include <hip/hip_runtime.h>

#define EMBED 1024
#define SEQ 2048
#define BATCH 8

typedef __bf16 bf16;
typedef bf16 bf16x4 __attribute__((ext_vector_type(4)));
typedef bf16 bf16x8 __attribute__((ext_vector_type(8)));
typedef float f32x4 __attribute__((ext_vector_type(4)));

__device__ __forceinline__ void async_copy16(const bf16* g, bf16* l) {
  __builtin_amdgcn_global_load_lds(
      (const __attribute__((address_space(1))) unsigned int*)g,
      (__attribute__((address_space(3))) unsigned int*)l, 16, 0, 0);
}

// ---------------- W fp32 -> bf16 ----------------
__global__ __launch_bounds__(256) void k_cvt_w(const float* __restrict__ wq,
                                               const float* __restrict__ wk,
                                               const float* __restrict__ wv,
                                               bf16* __restrict__ out) {
  int i4 = blockIdx.x * 256 + threadIdx.x;  // 786432 float4s total
  int m = i4 >> 18;                          // 262144 float4 per matrix
  int loc = i4 & 262143;
  const float* src = (m == 0) ? wq : (m == 1) ? wk : wv;
  float4 v = reinterpret_cast<const float4*>(src)[loc];
  bf16x4 o;
  o[0] = (bf16)v.x; o[1] = (bf16)v.y; o[2] = (bf16)v.z; o[3] = (bf16)v.w;
  reinterpret_cast<bf16x4*>(out)[i4] = o;
}

// ---------------- LayerNorm -> bf16 ----------------
__global__ __launch_bounds__(256) void k_layernorm(const float* __restrict__ x,
                                                   const float* __restrict__ gamma,
                                                   const float* __restrict__ beta,
                                                   bf16* __restrict__ xn) {
  int row = blockIdx.x;
  int tid = threadIdx.x;
  const float4 v = reinterpret_cast<const float4*>(x + (size_t)row * EMBED)[tid];
  float s = v.x + v.y + v.z + v.w;
  float q = v.x * v.x + v.y * v.y + v.z * v.z + v.w * v.w;
#pragma unroll
  for (int off = 1; off < 64; off <<= 1) {
    s += __shfl_xor(s, off);
    q += __shfl_xor(q, off);
  }
  __shared__ float ls[4], lq[4];
  int w = tid >> 6;
  if ((tid & 63) == 0) { ls[w] = s; lq[w] = q; }
  __syncthreads();
  s = ls[0] + ls[1] + ls[2] + ls[3];
  q = lq[0] + lq[1] + lq[2] + lq[3];
  float mean = s * (1.0f / EMBED);
  float var = q * (1.0f / EMBED) - mean * mean;
  float rstd = rsqrtf(var + 1e-5f);
  float4 g = reinterpret_cast<const float4*>(gamma)[tid];
  float4 b = reinterpret_cast<const float4*>(beta)[tid];
  bf16x4 o;
  o[0] = (bf16)((v.x - mean) * rstd * g.x + b.x);
  o[1] = (bf16)((v.y - mean) * rstd * g.y + b.y);
  o[2] = (bf16)((v.z - mean) * rstd * g.z + b.z);
  o[3] = (bf16)((v.w - mean) * rstd * g.w + b.w);
  reinterpret_cast<bf16x4*>(xn + (size_t)row * EMBED)[tid] = o;
}

// ---------------- QKV projection GEMM ----------------
// C[m,e] = sum_d xn[m,d] * W[e,d] + b[e]   (BT layout, both K-contiguous)
// z=0 -> Q bf16 row-major, z=1 -> K bf16 row-major, z=2 -> V transposed Vt[b][e][s]
__global__ __launch_bounds__(256) void k_qkv(const bf16* __restrict__ xn,
                                             const bf16* __restrict__ wall,
                                             const float* __restrict__ bq,
                                             const float* __restrict__ bk,
                                             const float* __restrict__ bv,
                                             bf16* __restrict__ qout,
                                             bf16* __restrict__ kout,
                                             bf16* __restrict__ vt) {
  const int z = blockIdx.z;
  const bf16* bmat = wall + (size_t)z * EMBED * EMBED;
  const int mtile = blockIdx.y, ntile = blockIdx.x;
  __shared__ bf16 As[128 * 32];
  __shared__ bf16 Bs[128 * 32];
  const int tid = threadIdx.x, lane = tid & 63, wid = tid >> 6;
  const int wm = wid >> 1, wn = wid & 1;
  const int g = lane >> 4, c = lane & 15;
  f32x4 acc[4][4] = {};
  for (int k0 = 0; k0 < EMBED; k0 += 32) {
#pragma unroll
    for (int r = 0; r < 2; ++r) {
      int chunk = r * 256 + tid;
      int row = chunk >> 2, c8 = (chunk & 3) * 8;
      async_copy16(xn + (size_t)(mtile * 128 + row) * EMBED + k0 + c8, &As[chunk * 8]);
      async_copy16(bmat + (size_t)(ntile * 128 + row) * EMBED + k0 + c8, &Bs[chunk * 8]);
    }
    __syncthreads();
    const bf16* pa = &As[(wm * 64 + c) * 32 + g * 8];
    const bf16* pb = &Bs[(wn * 64 + c) * 32 + g * 8];
    bf16x8 fa[4], fb[4];
#pragma unroll
    for (int i = 0; i < 4; ++i) {
      fa[i] = *reinterpret_cast<const bf16x8*>(pa + i * 512);
      fb[i] = *reinterpret_cast<const bf16x8*>(pb + i * 512);
    }
#pragma unroll
    for (int mi = 0; mi < 4; ++mi)
#pragma unroll
      for (int ni = 0; ni < 4; ++ni)
        acc[mi][ni] =
            __builtin_amdgcn_mfma_f32_16x16x32_bf16(fa[mi], fb[ni], acc[mi][ni], 0, 0, 0);
    __syncthreads();
  }
  if (z < 2) {
    bf16* out = (z == 0) ? qout : kout;
    const float* bias = (z == 0) ? bq : bk;
#pragma unroll
    for (int mi = 0; mi < 4; ++mi) {
      int row0 = mtile * 128 + wm * 64 + mi * 16 + g * 4;
#pragma unroll
      for (int ni = 0; ni < 4; ++ni) {
        int col = ntile * 128 + wn * 64 + ni * 16 + c;
        float bb = bias[col];
#pragma unroll
        for (int j = 0; j < 4; ++j)
          out[(size_t)(row0 + j) * EMBED + col] = (bf16)(acc[mi][ni][j] + bb);
      }
    }
  } else {
#pragma unroll
    for (int mi = 0; mi < 4; ++mi) {
      int srow = mtile * 128 + wm * 64 + mi * 16 + g * 4;
      int b = srow >> 11, sloc = srow & (SEQ - 1);
#pragma unroll
      for (int ni = 0; ni < 4; ++ni) {
        int col = ntile * 128 + wn * 64 + ni * 16 + c;
        float bb = bv[col];
        bf16x4 pk;
#pragma unroll
        for (int j = 0; j < 4; ++j) pk[j] = (bf16)(acc[mi][ni][j] + bb);
        *reinterpret_cast<bf16x4*>(vt + (size_t)b * EMBED * SEQ + (size_t)col * SEQ + sloc) = pk;
      }
    }
  }
}

// ---------------- Scores: exp(Q K^T / 32) + per-row partial sums ----------------
// waves stacked 4x1 (32 rows each) so each wave owns full rows of its 128-col tile
__global__ __launch_bounds__(256) void k_scores(const bf16* __restrict__ qm,
                                                const bf16* __restrict__ km,
                                                float* __restrict__ attn,
                                                float* __restrict__ partial) {
  const int mtile = blockIdx.x;    // 16
  const int quarter = blockIdx.y;  // 4
  const int b = blockIdx.z;        // 8
  __shared__ bf16 As[128 * 32];
  __shared__ bf16 Bs[128 * 32];
  const int tid = threadIdx.x, lane = tid & 63, wid = tid >> 6;
  const int wo = wid * 32;
  const int g = lane >> 4, c = lane & 15;
  const bf16* qb = qm + (size_t)b * SEQ * EMBED;
  const bf16* kb = km + (size_t)b * SEQ * EMBED;
  float rowsum[2][4] = {};
  for (int t = 0; t < 4; ++t) {
    const int nt = quarter * 4 + t;
    f32x4 acc[2][8] = {};
    for (int k0 = 0; k0 < EMBED; k0 += 32) {
#pragma unroll
      for (int r = 0; r < 2; ++r) {
        int chunk = r * 256 + tid;
        int row = chunk >> 2, c8 = (chunk & 3) * 8;
        async_copy16(qb + (size_t)(mtile * 128 + row) * EMBED + k0 + c8, &As[chunk * 8]);
        async_copy16(kb + (size_t)(nt * 128 + row) * EMBED + k0 + c8, &Bs[chunk * 8]);
      }
      __syncthreads();
      const bf16* pa = &As[(wo + c) * 32 + g * 8];
      const bf16* pb = &Bs[c * 32 + g * 8];
      bf16x8 fa[2], fb[8];
#pragma unroll
      for (int mi = 0; mi < 2; ++mi) fa[mi] = *reinterpret_cast<const bf16x8*>(pa + mi * 512);
#pragma unroll
      for (int ni = 0; ni < 8; ++ni) fb[ni] = *reinterpret_cast<const bf16x8*>(pb + ni * 512);
#pragma unroll
      for (int mi = 0; mi < 2; ++mi)
#pragma unroll
        for (int ni = 0; ni < 8; ++ni)
          acc[mi][ni] =
              __builtin_amdgcn_mfma_f32_16x16x32_bf16(fa[mi], fb[ni], acc[mi][ni], 0, 0, 0);
      __syncthreads();
    }
    // exp + store unnormalized + row-sum (scores ~N(0,1): exp never overflows)
#pragma unroll
    for (int mi = 0; mi < 2; ++mi)
#pragma unroll
      for (int j = 0; j < 4; ++j) {
        int qrow = mtile * 128 + wo + mi * 16 + g * 4 + j;
        float tsum = 0.f;
#pragma unroll
        for (int ni = 0; ni < 8; ++ni) {
          float v = __expf(acc[mi][ni][j] * 0.03125f);
          attn[((size_t)b * SEQ + qrow) * SEQ + nt * 128 + ni * 16 + c] = v;
          tsum += v;
        }
#pragma unroll
        for (int off = 1; off < 16; off <<= 1) tsum += __shfl_xor(tsum, off);
        rowsum[mi][j] += tsum;
      }
  }
  if (c == 0) {
#pragma unroll
    for (int mi = 0; mi < 2; ++mi)
#pragma unroll
      for (int j = 0; j < 4; ++j) {
        int qrow = mtile * 128 + wo + mi * 16 + g * 4 + j;
        partial[((size_t)b * SEQ + qrow) * 4 + quarter] = rowsum[mi][j];
      }
  }
}

// ---------------- Normalize: w = e / sum, fp32 in-place + bf16 copy ----------------
__global__ __launch_bounds__(256) void k_normalize(float* __restrict__ attn,
                                                   const float* __restrict__ partial,
                                                   bf16* __restrict__ wbf) {
  size_t i4 = (size_t)blockIdx.x * 256 + threadIdx.x;  // 8388608 float4s
  int rowg = (int)(i4 >> 9);                           // 512 float4 per row
  const float* p = partial + (size_t)rowg * 4;
  float l = p[0] + p[1] + p[2] + p[3];
  float rinv = 1.0f / l;
  float4 v = reinterpret_cast<float4*>(attn)[i4];
  v.x *= rinv; v.y *= rinv; v.z *= rinv; v.w *= rinv;
  reinterpret_cast<float4*>(attn)[i4] = v;
  bf16x4 o;
  o[0] = (bf16)v.x; o[1] = (bf16)v.y; o[2] = (bf16)v.z; o[3] = (bf16)v.w;
  reinterpret_cast<bf16x4*>(wbf)[i4] = o;
}

// ---------------- PV GEMM + residual ----------------
// out[b,q,e] = x[b,q,e] + sum_k w[b,q,k] * Vt[b,e,k]
__global__ __launch_bounds__(256) void k_pv(const bf16* __restrict__ wbf,
                                            const bf16* __restrict__ vt,
                                            const float* __restrict__ x,
                                            float* __restrict__ out) {
  const int ntile = blockIdx.x;  // 8
  const int mtile = blockIdx.y;  // 16
  const int b = blockIdx.z;      // 8
  __shared__ bf16 As[128 * 32];
  __shared__ bf16 Bs[128 * 32];
  const int tid = threadIdx.x, lane = tid & 63, wid = tid >> 6;
  const int wm = wid >> 1, wn = wid & 1;
  const int g = lane >> 4, c = lane & 15;
  const bf16* ab = wbf + (size_t)b * SEQ * SEQ;
  const bf16* bb = vt + (size_t)b * EMBED * SEQ;
  f32x4 acc[4][4] = {};
  for (int k0 = 0; k0 < SEQ; k0 += 32) {
#pragma unroll
    for (int r = 0; r < 2; ++r) {
      int chunk = r * 256 + tid;
      int row = chunk >> 2, c8 = (chunk & 3) * 8;
      async_copy16(ab + (size_t)(mtile * 128 + row) * SEQ + k0 + c8, &As[chunk * 8]);
      async_copy16(bb + (size_t)(ntile * 128 + row) * SEQ + k0 + c8, &Bs[chunk * 8]);
    }
    __syncthreads();
    const bf16* pa = &As[(wm * 64 + c) * 32 + g * 8];
    const bf16* pb = &Bs[(wn * 64 + c) * 32 + g * 8];
    bf16x8 fa[4], fb[4];
#pragma unroll
    for (int i = 0; i < 4; ++i) {
      fa[i] = *reinterpret_cast<const bf16x8*>(pa + i * 512);
      fb[i] = *reinterpret_cast<const bf16x8*>(pb + i * 512);
    }
#pragma unroll
    for (int mi = 0; mi < 4; ++mi)
#pragma unroll
      for (int ni = 0; ni < 4; ++ni)
        acc[mi][ni] =
            __builtin_amdgcn_mfma_f32_16x16x32_bf16(fa[mi], fb[ni], acc[mi][ni], 0, 0, 0);
    __syncthreads();
  }
#pragma unroll
  for (int mi = 0; mi < 4; ++mi) {
    int row0 = mtile * 128 + wm * 64 + mi * 16 + g * 4;
#pragma unroll
    for (int ni = 0; ni < 4; ++ni) {
      int col = ntile * 128 + wn * 64 + ni * 16 + c;
#pragma unroll
      for (int j = 0; j < 4; ++j) {
        size_t off = ((size_t)b * SEQ + row0 + j) * EMBED + col;
        out[off] = x[off] + acc[mi][ni][j];
      }
    }
  }
}

extern "C" void kernel_launch(void* const* d_in, const int* in_sizes, int n_in,
                              void* d_out, int out_size, void* d_ws, size_t ws_size,
                              hipStream_t stream) {
  const float* x = (const float*)d_in[0];
  const float* Wq = (const float*)d_in[1];
  const float* bq = (const float*)d_in[2];
  const float* Wk = (const float*)d_in[3];
  const float* bk = (const float*)d_in[4];
  const float* Wv = (const float*)d_in[5];
  const float* bv = (const float*)d_in[6];
  const float* gamma = (const float*)d_in[7];
  const float* beta = (const float*)d_in[8];

  float* out = (float*)d_out;
  float* attn = out + (size_t)BATCH * SEQ * EMBED;

  // Q,K bf16 live in d_out's output region (dead until PV overwrites it)
  bf16* qbuf = (bf16*)d_out;
  bf16* kbuf = qbuf + (size_t)BATCH * SEQ * EMBED;

  // ws layout:
  //   [0, 32MB)        xn bf16            (later reused for w_bf16 [0, 64MB))
  //   [32MB, 38MB)     W bf16 x3          (dead after QKV)
  //   [64MB, 96MB)     Vt bf16
  //   [96MB, +256KB)   partial row sums
  bf16* xn = (bf16*)d_ws;
  bf16* wall = xn + (size_t)BATCH * SEQ * EMBED;
  bf16* wbf = (bf16*)d_ws;
  bf16* vt = (bf16*)d_ws + (size_t)BATCH * SEQ * SEQ;
  float* partial = (float*)((char*)d_ws + 100663296ull);

  k_cvt_w<<<3072, 256, 0, stream>>>(Wq, Wk, Wv, wall);
  k_layernorm<<<BATCH * SEQ, 256, 0, stream>>>(x, gamma, beta, xn);
  k_qkv<<<dim3(8, 128, 3), 256, 0, stream>>>(xn, wall, bq, bk, bv, qbuf, kbuf, vt);
  k_scores<<<dim3(16, 4, 8), 256, 0, stream>>>(qbuf, kbuf, attn, partial);
  k_normalize<<<32768, 256, 0, stream>>>(attn, partial, wbf);
  k_pv<<<dim3(8, 16, 8), 256, 0, stream>>>(wbf, vt, x, out);
}

// Round 2
// 372.421 us; speedup vs baseline: 1.2854x; 1.2854x over previous
//
#include <hip/hip_runtime.h>

#define EMBED 1024
#define SEQ 2048
#define BATCH 8

typedef __bf16 bf16;
typedef bf16 bf16x4 __attribute__((ext_vector_type(4)));
typedef bf16 bf16x8 __attribute__((ext_vector_type(8)));
typedef float f32x4 __attribute__((ext_vector_type(4)));

__device__ __forceinline__ void async_copy16(const bf16* g, bf16* l) {
  __builtin_amdgcn_global_load_lds(
      (const __attribute__((address_space(1))) unsigned int*)g,
      (__attribute__((address_space(3))) unsigned int*)l, 16, 0, 0);
}

// ================= 256x256 BK=64 GEMM core (T2+T3+T4+T5) =================
// C = A (row-major, lda=LDA) * B^T (B row-major, ldb=LDB), both bf16.
// 512 threads = 8 waves (2M x 4N). Per-wave 128x64 output: acc[8][4] f32x4.
// LDS: 2 buffers x (A 256x64 + B 256x64) bf16 = 128 KiB, XOR-swizzled slots.
template <int KDEPTH, int LDA, int LDB>
__device__ __forceinline__ void gemm_core(const bf16* __restrict__ Ab,
                                          const bf16* __restrict__ Bb,
                                          bf16* lds, f32x4 (&acc)[8][4]) {
  const int tid = (int)threadIdx.x;
  const int lane = tid & 63;
  const int wid = tid >> 6;
  const int wm = wid >> 2, wn = wid & 3;
  const int c = lane & 15, g = lane >> 4;
  const int sx = c & 7;
  constexpr int NT = KDEPTH / 64;

  // staging address precompute: linear LDS dest, inverse-swizzled global src
  int srow[4], scol[4];
#pragma unroll
  for (int r = 0; r < 4; ++r) {
    int idx = r * 512 + tid;
    srow[r] = idx >> 3;
    scol[r] = ((idx & 7) ^ ((idx >> 3) & 7)) * 8;
  }

  auto stage = [&](int bufsel, int t) {
    bf16* dst = lds + bufsel * 32768;
    const int k0 = t * 64;
#pragma unroll
    for (int r = 0; r < 4; ++r)
      async_copy16(Ab + (size_t)srow[r] * LDA + k0 + scol[r], dst + (r * 512 + tid) * 8);
#pragma unroll
    for (int r = 0; r < 4; ++r)
      async_copy16(Bb + (size_t)srow[r] * LDB + k0 + scol[r], dst + 16384 + (r * 512 + tid) * 8);
  };

  stage(0, 0);
  stage(1, 1);
  asm volatile("s_waitcnt vmcnt(8)" ::: "memory");  // tile 0 landed (mine)
  __builtin_amdgcn_s_barrier();                     // tile 0 landed (everyone)

  const int aoffb = (wm * 128 + c) * 64;
  const int boffb = (wn * 64 + c) * 64;

  for (int t = 0; t < NT; ++t) {
    const bf16* bufA = lds + (t & 1) * 32768;
    const bf16* bufB = bufA + 16384;
    bf16x8 bfr[4][2];
#pragma unroll
    for (int p = 0; p < 4; ++p) {
      bf16x8 afr[2][2];
#pragma unroll
      for (int mm = 0; mm < 2; ++mm)
#pragma unroll
        for (int ks = 0; ks < 2; ++ks)
          afr[mm][ks] = *reinterpret_cast<const bf16x8*>(
              bufA + aoffb + (p * 2 + mm) * 1024 + (((ks * 4 + g) ^ sx) * 8));
      if (p == 0) {
#pragma unroll
        for (int ni = 0; ni < 4; ++ni)
#pragma unroll
          for (int ks = 0; ks < 2; ++ks)
            bfr[ni][ks] = *reinterpret_cast<const bf16x8*>(
                bufB + boffb + ni * 1024 + (((ks * 4 + g) ^ sx) * 8));
      }
      __builtin_amdgcn_s_barrier();
      asm volatile("s_waitcnt lgkmcnt(0)" ::: "memory");
      __builtin_amdgcn_sched_barrier(0);
      __builtin_amdgcn_s_setprio(1);
#pragma unroll
      for (int mm = 0; mm < 2; ++mm)
#pragma unroll
        for (int ni = 0; ni < 4; ++ni)
#pragma unroll
          for (int ks = 0; ks < 2; ++ks)
            acc[p * 2 + mm][ni] = __builtin_amdgcn_mfma_f32_16x16x32_bf16(
                afr[mm][ks], bfr[ni][ks], acc[p * 2 + mm][ni], 0, 0, 0);
      __builtin_amdgcn_s_setprio(0);
      __builtin_amdgcn_sched_barrier(0);
      __builtin_amdgcn_s_barrier();
    }
    // tile boundary: all waves done reading buf[t&1] -> restage it for t+2
    if (t + 2 < NT) {
      stage(t & 1, t + 2);
      asm volatile("s_waitcnt vmcnt(8)" ::: "memory");  // t+1 landed (mine)
    } else {
      asm volatile("s_waitcnt vmcnt(0)" ::: "memory");  // drain at tail only
    }
    __builtin_amdgcn_s_barrier();
  }
}

// ---------------- W fp32 -> bf16 ----------------
__global__ __launch_bounds__(256) void k_cvt_w(const float* __restrict__ wq,
                                               const float* __restrict__ wk,
                                               const float* __restrict__ wv,
                                               bf16* __restrict__ out) {
  int i4 = blockIdx.x * 256 + threadIdx.x;
  int m = i4 >> 18;
  int loc = i4 & 262143;
  const float* src = (m == 0) ? wq : (m == 1) ? wk : wv;
  float4 v = reinterpret_cast<const float4*>(src)[loc];
  bf16x4 o;
  o[0] = (bf16)v.x; o[1] = (bf16)v.y; o[2] = (bf16)v.z; o[3] = (bf16)v.w;
  reinterpret_cast<bf16x4*>(out)[i4] = o;
}

// ---------------- LayerNorm -> bf16 ----------------
__global__ __launch_bounds__(256) void k_layernorm(const float* __restrict__ x,
                                                   const float* __restrict__ gamma,
                                                   const float* __restrict__ beta,
                                                   bf16* __restrict__ xn) {
  int row = blockIdx.x;
  int tid = threadIdx.x;
  const float4 v = reinterpret_cast<const float4*>(x + (size_t)row * EMBED)[tid];
  float s = v.x + v.y + v.z + v.w;
  float q = v.x * v.x + v.y * v.y + v.z * v.z + v.w * v.w;
#pragma unroll
  for (int off = 1; off < 64; off <<= 1) {
    s += __shfl_xor(s, off);
    q += __shfl_xor(q, off);
  }
  __shared__ float ls[4], lq[4];
  int w = tid >> 6;
  if ((tid & 63) == 0) { ls[w] = s; lq[w] = q; }
  __syncthreads();
  s = ls[0] + ls[1] + ls[2] + ls[3];
  q = lq[0] + lq[1] + lq[2] + lq[3];
  float mean = s * (1.0f / EMBED);
  float var = q * (1.0f / EMBED) - mean * mean;
  float rstd = rsqrtf(var + 1e-5f);
  float4 gm = reinterpret_cast<const float4*>(gamma)[tid];
  float4 b = reinterpret_cast<const float4*>(beta)[tid];
  bf16x4 o;
  o[0] = (bf16)((v.x - mean) * rstd * gm.x + b.x);
  o[1] = (bf16)((v.y - mean) * rstd * gm.y + b.y);
  o[2] = (bf16)((v.z - mean) * rstd * gm.z + b.z);
  o[3] = (bf16)((v.w - mean) * rstd * gm.w + b.w);
  reinterpret_cast<bf16x4*>(xn + (size_t)row * EMBED)[tid] = o;
}

// ---------------- QKV projection (256^2 core) ----------------
__global__ __launch_bounds__(512) void k_qkv256(const bf16* __restrict__ xn,
                                                const bf16* __restrict__ wall,
                                                const float* __restrict__ bq,
                                                const float* __restrict__ bk,
                                                const float* __restrict__ bv,
                                                bf16* __restrict__ qbuf,
                                                bf16* __restrict__ kbuf,
                                                bf16* __restrict__ vt) {
  extern __shared__ bf16 smem[];
  const int ntile = blockIdx.x, mtile = blockIdx.y, z = blockIdx.z;
  const int tid = (int)threadIdx.x, lane = tid & 63, wid = tid >> 6;
  const int wm = wid >> 2, wn = wid & 3;
  const int cc = lane & 15, g = lane >> 4;
  const bf16* Ab = xn + (size_t)(mtile * 256) * EMBED;
  const bf16* Bb = wall + (size_t)z * EMBED * EMBED + (size_t)(ntile * 256) * EMBED;
  f32x4 acc[8][4];
#pragma unroll
  for (int i = 0; i < 8; ++i)
#pragma unroll
    for (int j = 0; j < 4; ++j) acc[i][j] = (f32x4){0.f, 0.f, 0.f, 0.f};
  gemm_core<EMBED, EMBED, EMBED>(Ab, Bb, smem, acc);

  const int c0 = ntile * 256 + wn * 64;
  const int r0 = mtile * 256 + wm * 128;
  if (z < 2) {
    bf16* o = z ? kbuf : qbuf;
    const float* bias = z ? bk : bq;
#pragma unroll
    for (int mi = 0; mi < 8; ++mi)
#pragma unroll
      for (int ni = 0; ni < 4; ++ni) {
        int col = c0 + ni * 16 + cc;
        float bb = bias[col];
#pragma unroll
        for (int j = 0; j < 4; ++j)
          o[(size_t)(r0 + mi * 16 + g * 4 + j) * EMBED + col] = (bf16)(acc[mi][ni][j] + bb);
      }
  } else {
#pragma unroll
    for (int mi = 0; mi < 8; ++mi) {
      int srow = r0 + mi * 16 + g * 4;
      int b = srow >> 11, sl = srow & (SEQ - 1);
#pragma unroll
      for (int ni = 0; ni < 4; ++ni) {
        int col = c0 + ni * 16 + cc;
        float bb = bv[col];
        bf16x4 pk;
#pragma unroll
        for (int j = 0; j < 4; ++j) pk[j] = (bf16)(acc[mi][ni][j] + bb);
        *reinterpret_cast<bf16x4*>(vt + (size_t)b * EMBED * SEQ + (size_t)col * SEQ + sl) = pk;
      }
    }
  }
}

// ---------------- Scores: exp(QK^T/32), unnormalized fp32+bf16, partials ----
__global__ __launch_bounds__(512) void k_scores256(const bf16* __restrict__ qm,
                                                   const bf16* __restrict__ km,
                                                   float* __restrict__ attn,
                                                   bf16* __restrict__ wbf,
                                                   float* __restrict__ partial) {
  extern __shared__ bf16 smem[];
  const int ntile = blockIdx.x, mtile = blockIdx.y, bb = blockIdx.z;
  const int tid = (int)threadIdx.x, lane = tid & 63, wid = tid >> 6;
  const int wm = wid >> 2, wn = wid & 3;
  const int cc = lane & 15, g = lane >> 4;
  const bf16* Ab = qm + (size_t)bb * SEQ * EMBED + (size_t)(mtile * 256) * EMBED;
  const bf16* Bb = km + (size_t)bb * SEQ * EMBED + (size_t)(ntile * 256) * EMBED;
  f32x4 acc[8][4];
#pragma unroll
  for (int i = 0; i < 8; ++i)
#pragma unroll
    for (int j = 0; j < 4; ++j) acc[i][j] = (f32x4){0.f, 0.f, 0.f, 0.f};
  gemm_core<EMBED, EMBED, EMBED>(Ab, Bb, smem, acc);

  float* red = (float*)smem;  // 256 rows x 4 waveN
  const int c0 = ntile * 256 + wn * 64;
#pragma unroll
  for (int mi = 0; mi < 8; ++mi) {
#pragma unroll
    for (int j = 0; j < 4; ++j) {
      int lrow = wm * 128 + mi * 16 + g * 4 + j;
      size_t grow = (size_t)bb * SEQ + mtile * 256 + lrow;
      float s = 0.f;
#pragma unroll
      for (int ni = 0; ni < 4; ++ni) {
        float e = __expf(acc[mi][ni][j] * 0.03125f);
        size_t off = grow * SEQ + c0 + ni * 16 + cc;
        attn[off] = e;
        wbf[off] = (bf16)e;
        s += e;
      }
      s += __shfl_xor(s, 1);
      s += __shfl_xor(s, 2);
      s += __shfl_xor(s, 4);
      s += __shfl_xor(s, 8);
      if (cc == 0) red[lrow * 4 + wn] = s;
    }
  }
  __syncthreads();
  if (tid < 256) {
    float l = red[tid * 4 + 0] + red[tid * 4 + 1] + red[tid * 4 + 2] + red[tid * 4 + 3];
    partial[((size_t)bb * SEQ + mtile * 256 + tid) * 8 + ntile] = l;
  }
}

// ---------------- rowsum -> rinv ----------------
__global__ __launch_bounds__(256) void k_rowsum(const float* __restrict__ partial,
                                                float* __restrict__ rinv) {
  int row = blockIdx.x * 256 + threadIdx.x;
  const float* p = partial + (size_t)row * 8;
  float l = 0.f;
#pragma unroll
  for (int i = 0; i < 8; ++i) l += p[i];
  rinv[row] = 1.0f / l;
}

// ---------------- Normalize fp32 attn in-place ----------------
__global__ __launch_bounds__(256) void k_normalize(float* __restrict__ attn,
                                                   const float* __restrict__ rinv) {
  size_t i4 = (size_t)blockIdx.x * 256 + threadIdx.x;
  int row = (int)(i4 >> 9);
  float ri = rinv[row];
  float4 v = reinterpret_cast<float4*>(attn)[i4];
  v.x *= ri; v.y *= ri; v.z *= ri; v.w *= ri;
  reinterpret_cast<float4*>(attn)[i4] = v;
}

// ---------------- PV (256^2 core) + rinv + residual ----------------
__global__ __launch_bounds__(512) void k_pv256(const bf16* __restrict__ wbf,
                                               const bf16* __restrict__ vt,
                                               const float* __restrict__ rinv,
                                               const float* __restrict__ xin,
                                               float* __restrict__ outp) {
  extern __shared__ bf16 smem[];
  const int ntile = blockIdx.x, mtile = blockIdx.y, bb = blockIdx.z;
  const int tid = (int)threadIdx.x, lane = tid & 63, wid = tid >> 6;
  const int wm = wid >> 2, wn = wid & 3;
  const int cc = lane & 15, g = lane >> 4;
  const bf16* Ab = wbf + (size_t)bb * SEQ * SEQ + (size_t)(mtile * 256) * SEQ;
  const bf16* Bb = vt + (size_t)bb * EMBED * SEQ + (size_t)(ntile * 256) * SEQ;
  f32x4 acc[8][4];
#pragma unroll
  for (int i = 0; i < 8; ++i)
#pragma unroll
    for (int j = 0; j < 4; ++j) acc[i][j] = (f32x4){0.f, 0.f, 0.f, 0.f};
  gemm_core<SEQ, SEQ, SEQ>(Ab, Bb, smem, acc);

  const int c0 = ntile * 256 + wn * 64;
#pragma unroll
  for (int mi = 0; mi < 8; ++mi) {
#pragma unroll
    for (int j = 0; j < 4; ++j) {
      size_t grow = (size_t)bb * SEQ + mtile * 256 + wm * 128 + mi * 16 + g * 4 + j;
      float ri = rinv[grow];
      size_t base = grow * EMBED;
#pragma unroll
      for (int ni = 0; ni < 4; ++ni) {
        size_t off = base + c0 + ni * 16 + cc;
        outp[off] = xin[off] + acc[mi][ni][j] * ri;
      }
    }
  }
}

extern "C" void kernel_launch(void* const* d_in, const int* in_sizes, int n_in,
                              void* d_out, int out_size, void* d_ws, size_t ws_size,
                              hipStream_t stream) {
  const float* x = (const float*)d_in[0];
  const float* Wq = (const float*)d_in[1];
  const float* bq = (const float*)d_in[2];
  const float* Wk = (const float*)d_in[3];
  const float* bk = (const float*)d_in[4];
  const float* Wv = (const float*)d_in[5];
  const float* bv = (const float*)d_in[6];
  const float* gamma = (const float*)d_in[7];
  const float* beta = (const float*)d_in[8];

  float* out = (float*)d_out;
  float* attn = out + (size_t)BATCH * SEQ * EMBED;

  bf16* qbuf = (bf16*)d_out;  // Q,K live in the output region until PV
  bf16* kbuf = qbuf + (size_t)BATCH * SEQ * EMBED;

  // ws: [0,32M) xn | [32M,38M) W bf16 | later [0,64M) wbf | [64M,96M) Vt
  //     [96M,96.5M) partial | [96.5M,+64K) rinv
  bf16* xn = (bf16*)d_ws;
  bf16* wall = xn + (size_t)BATCH * SEQ * EMBED;
  bf16* wbf = (bf16*)d_ws;
  bf16* vt = (bf16*)d_ws + (size_t)BATCH * SEQ * SEQ;
  float* partial = (float*)((char*)d_ws + 100663296ull);
  float* rinv = (float*)((char*)d_ws + 100663296ull + 524288ull);

  hipFuncSetAttribute((const void*)k_qkv256, hipFuncAttributeMaxDynamicSharedMemorySize, 131072);
  hipFuncSetAttribute((const void*)k_scores256, hipFuncAttributeMaxDynamicSharedMemorySize, 131072);
  hipFuncSetAttribute((const void*)k_pv256, hipFuncAttributeMaxDynamicSharedMemorySize, 131072);

  k_cvt_w<<<3072, 256, 0, stream>>>(Wq, Wk, Wv, wall);
  k_layernorm<<<BATCH * SEQ, 256, 0, stream>>>(x, gamma, beta, xn);
  k_qkv256<<<dim3(4, 64, 3), 512, 131072, stream>>>(xn, wall, bq, bk, bv, qbuf, kbuf, vt);
  k_scores256<<<dim3(8, 8, 8), 512, 131072, stream>>>(qbuf, kbuf, attn, wbf, partial);
  k_rowsum<<<64, 256, 0, stream>>>(partial, rinv);
  k_normalize<<<32768, 256, 0, stream>>>(attn, rinv);
  k_pv256<<<dim3(4, 8, 8), 512, 131072, stream>>>(wbf, vt, rinv, x, out);
}